// Round 8
// baseline (536.535 us; speedup 1.0000x reference)
//
#include <hip/hip_runtime.h>

#define E_ 8
#define H_ 1024
#define I_ 512
#define NE 9            // 8 routed + 1 shared
#define NTOK 8192
#define NROWS 40960     // 4*NTOK routed + NTOK shared compacted rows

typedef __bf16 bf16;
typedef __bf16 bf16x8 __attribute__((ext_vector_type(8)));
typedef __bf16 bf16x4 __attribute__((ext_vector_type(4)));
typedef float f32x4 __attribute__((ext_vector_type(4)));

__device__ __forceinline__ void gload16(const bf16* g, bf16* l) {
  __builtin_amdgcn_global_load_lds(
      (const __attribute__((address_space(1))) void*)g,
      (__attribute__((address_space(3))) void*)l,
      16, 0, 0);
}

// ---------------- prep: convert (x->bf16) + weight transpose + router ----------------
#define PREP_CONV 2048
#define PREP_TRANS 3456
__global__ __launch_bounds__(256) void prep_kernel(
    const float* __restrict__ x, const float* __restrict__ gw,
    const float* __restrict__ bias,
    const float* __restrict__ Wg, const float* __restrict__ Wu,
    const float* __restrict__ Wd, const float* __restrict__ Wgs,
    const float* __restrict__ Wus, const float* __restrict__ Wds,
    bf16* __restrict__ xb, bf16* __restrict__ BgT, bf16* __restrict__ BuT,
    bf16* __restrict__ WdT, int4* __restrict__ topk_e, float4* __restrict__ topk_w) {
  __shared__ bf16 tile[64][66];
  int bid = blockIdx.x;
  int t = threadIdx.x;

  if (bid < PREP_CONV) {
    size_t base = (size_t)bid * 1024 + t;
#pragma unroll
    for (int j = 0; j < 4; j++) {
      f32x4 v = ((const f32x4*)x)[base + 256 * j];
      bf16x4 o = {(bf16)v.x, (bf16)v.y, (bf16)v.z, (bf16)v.w};
      ((bf16x4*)xb)[base + 256 * j] = o;
    }
    return;
  }
  if (bid < PREP_CONV + PREP_TRANS) {
    int b = bid - PREP_CONV;
    int job = b >> 7;
    int tl = b & 127;
    const float* src;
    bf16* dst;
    int C, dst_ld, tr, tc;
    if (job < 18) {
      int e = job % 9;
      if (job < 9) src = (e < 8) ? Wg + (size_t)e * H_ * I_ : Wgs;
      else         src = (e < 8) ? Wu + (size_t)e * H_ * I_ : Wus;
      dst = ((job < 9) ? BgT : BuT) + (size_t)e * I_ * H_;
      C = I_; dst_ld = H_;
      tr = tl >> 3; tc = tl & 7;
    } else {
      int e = job - 18;
      src = (e < 8) ? Wd + (size_t)e * I_ * H_ : Wds;
      dst = WdT + (size_t)e * H_ * I_;
      C = H_; dst_ld = I_;
      tr = tl >> 4; tc = tl & 15;
    }
    int lx = t & 63, ly = t >> 6;
#pragma unroll
    for (int j = 0; j < 16; j++) {
      int rl = j * 4 + ly;
      tile[lx][rl] = (bf16)src[(size_t)(tr * 64 + rl) * C + tc * 64 + lx];
    }
    __syncthreads();
#pragma unroll
    for (int j = 0; j < 16; j++) {
      int cl = j * 4 + ly;
      dst[(size_t)(tc * 64 + cl) * dst_ld + tr * 64 + lx] = tile[cl][lx];
    }
    return;
  }
  int rb = bid - PREP_CONV - PREP_TRANS;
  int l = t & 63, w = t >> 6;
  int n = rb * 4 + w;
  const f32x4* xr = (const f32x4*)(x + (size_t)n * H_ + l * 16);
  float xv[16];
#pragma unroll
  for (int q = 0; q < 4; q++) {
    f32x4 v = xr[q];
    xv[q * 4 + 0] = v.x; xv[q * 4 + 1] = v.y; xv[q * 4 + 2] = v.z; xv[q * 4 + 3] = v.w;
  }
  float acc[E_];
#pragma unroll
  for (int e = 0; e < E_; e++) {
    const f32x4* gr = (const f32x4*)(gw + e * H_ + l * 16);
    float a = 0.f;
#pragma unroll
    for (int q = 0; q < 4; q++) {
      f32x4 g = gr[q];
      a += xv[q * 4 + 0] * g.x + xv[q * 4 + 1] * g.y + xv[q * 4 + 2] * g.z + xv[q * 4 + 3] * g.w;
    }
    acc[e] = a;
  }
#pragma unroll
  for (int off = 32; off > 0; off >>= 1) {
    float tmp[E_];
#pragma unroll
    for (int e = 0; e < E_; e++) tmp[e] = __shfl_xor(acc[e], off, 64);
#pragma unroll
    for (int e = 0; e < E_; e++) acc[e] += tmp[e];
  }
  if (l == 0) {
    float s[E_], sc[E_];
#pragma unroll
    for (int e = 0; e < E_; e++) {
      s[e] = 1.f / (1.f + __expf(-acc[e]));
      sc[e] = s[e] + bias[e];
    }
    float gs[4];
#pragma unroll
    for (int g = 0; g < 4; g++) gs[g] = sc[2 * g] + sc[2 * g + 1];
    int g0 = 0;
    for (int g = 1; g < 4; g++) if (gs[g] > gs[g0]) g0 = g;
    int g1 = -1;
    for (int g = 0; g < 4; g++) {
      if (g == g0) continue;
      if (g1 < 0 || gs[g] > gs[g1]) g1 = g;
    }
    int es[4] = {2 * g0, 2 * g0 + 1, 2 * g1, 2 * g1 + 1};
    float wsum = 1e-20f;
    for (int j = 0; j < 4; j++) wsum += s[es[j]];
    float inv = 2.5f / wsum;
    topk_e[n] = (int4){es[0], es[1], es[2], es[3]};
    topk_w[n] = (float4){s[es[0]] * inv, s[es[1]] * inv, s[es[2]] * inv, s[es[3]] * inv};
  }
}

// ---------------- compaction ----------------
__global__ __launch_bounds__(256) void compact_kernel(
    const int4* __restrict__ topk_e, const float4* __restrict__ topk_w,
    int* __restrict__ cnt, int* __restrict__ idx, float* __restrict__ cwp,
    int* __restrict__ tokpos) {
  __shared__ int hist[E_];
  __shared__ int base[E_];
  int t = threadIdx.x;
  if (t < E_) hist[t] = 0;
  __syncthreads();
  int n = blockIdx.x * 256 + t;
  int4 e4 = topk_e[n];
  float4 w4 = topk_w[n];
  int le[4] = {e4.x, e4.y, e4.z, e4.w};
  float lw[4] = {w4.x, w4.y, w4.z, w4.w};
  int lpos[4];
#pragma unroll
  for (int j = 0; j < 4; j++) lpos[j] = atomicAdd(&hist[le[j]], 1);
  __syncthreads();
  if (t < E_) base[t] = atomicAdd(&cnt[t], hist[t]);
  __syncthreads();
#pragma unroll
  for (int j = 0; j < 4; j++) {
    int p = base[le[j]] + lpos[j];
    idx[le[j] * NTOK + p] = n;
    cwp[le[j] * NTOK + p] = lw[j];
    tokpos[n * 4 + j] = (le[j] << 13) | p;
  }
}

// XCD-affine work decode: blocks with blockIdx%8==g (same XCD under the %8
// round-robin heuristic) process expert g's tiles, then a g-stripe of the
// shared expert's tiles. j is the per-XCD work index (grid-stride).
__device__ __forceinline__ bool xcd_decode(const int* cnt, int g, int j, int ntiles,
                                           int& e, int& m0, int& ne, int& off_e, int& n0) {
  int ne_g = cnt[g];
  int Tg = ((ne_g + 127) >> 7) * ntiles;
  if (j < Tg) {
    e = g; ne = ne_g;
    m0 = (j / ntiles) * 128; n0 = (j % ntiles) * 128;
    int off = 0;
    for (int ee = 0; ee < E_; ee++) off += (ee < g) ? cnt[ee] : 0;
    off_e = off;
    return true;
  }
  int s = (j - Tg) * 8 + g;
  if (s < 64 * ntiles) {
    e = 8; ne = NTOK; off_e = 4 * NTOK;
    m0 = (s / ntiles) * 128; n0 = (s % ntiles) * 128;
    return true;
  }
  return false;
}

// LDS tiles [128][64] bf16, XOR-swizzled in 16B chunks (see R2 notes):
// 2-way bank conflicts only (free).

// ---------------- GEMM1 (grouped, XCD-affine): Tc[off_e+p] = cw*silu(X Wg_e)*(X Wu_e) ----------------
__global__ __launch_bounds__(256, 3) void gemm1_kernel(
    const bf16* __restrict__ X, const bf16* __restrict__ BgT,
    const bf16* __restrict__ BuT, const int* __restrict__ idx,
    const float* __restrict__ cwp, const int* __restrict__ cnt,
    bf16* __restrict__ Tc) {
  __shared__ bf16 As[128 * 64], Bgs[128 * 64], Bus[128 * 64];
  int t = threadIdx.x;
  int l = t & 63, w = t >> 6;
  int wm = w >> 1, wn = w & 1;
  int srow = t >> 3;
  int scol = (((t & 7) ^ ((t >> 3) & 7)) * 8);
  bf16* la = As + w * 512;
  bf16* lg = Bgs + w * 512;
  bf16* lu = Bus + w * 512;
  int g = blockIdx.x & 7;
  int S = gridDim.x >> 3;

  for (int j = blockIdx.x >> 3; ; j += S) {
    int e, m0, ne, off_e, n0;
    if (!xcd_decode(cnt, g, j, 4, e, m0, ne, off_e, n0)) break;

    f32x4 accg[4][4], accu[4][4];
#pragma unroll
    for (int mi = 0; mi < 4; mi++)
#pragma unroll
      for (int ni = 0; ni < 4; ni++) {
        accg[mi][ni] = (f32x4){0.f, 0.f, 0.f, 0.f};
        accu[mi][ni] = (f32x4){0.f, 0.f, 0.f, 0.f};
      }

    int rid[4];
#pragma unroll
    for (int i = 0; i < 4; i++) {
      int r = m0 + srow + 32 * i;
      rid[i] = (e < 8) ? ((r < ne) ? idx[e * NTOK + r] : 0) : r;
    }
    const bf16* gg = BgT + (size_t)e * I_ * H_ + (size_t)(n0 + srow) * H_ + scol;
    const bf16* gu = BuT + (size_t)e * I_ * H_ + (size_t)(n0 + srow) * H_ + scol;

    for (int k0 = 0; k0 < H_; k0 += 64) {
#pragma unroll
      for (int i = 0; i < 4; i++) {
        gload16(X + (size_t)rid[i] * H_ + scol + k0, la + i * 2048);
        gload16(gg + (size_t)i * 32 * H_ + k0, lg + i * 2048);
        gload16(gu + (size_t)i * 32 * H_ + k0, lu + i * 2048);
      }
      __syncthreads();
#pragma unroll
      for (int ks = 0; ks < 2; ks++) {
        int ko = (((ks * 4 + (l >> 4)) ^ (l & 7)) * 8);
        int ar = wm * 64 + (l & 15);
        int br = wn * 64 + (l & 15);
        bf16x8 af[4], bg[4], bu[4];
#pragma unroll
        for (int mi = 0; mi < 4; mi++)
          af[mi] = *(const bf16x8*)(As + (ar + mi * 16) * 64 + ko);
#pragma unroll
        for (int ni = 0; ni < 4; ni++) {
          bg[ni] = *(const bf16x8*)(Bgs + (br + ni * 16) * 64 + ko);
          bu[ni] = *(const bf16x8*)(Bus + (br + ni * 16) * 64 + ko);
        }
#pragma unroll
        for (int mi = 0; mi < 4; mi++)
#pragma unroll
          for (int ni = 0; ni < 4; ni++) {
            accg[mi][ni] = __builtin_amdgcn_mfma_f32_16x16x32_bf16(af[mi], bg[ni], accg[mi][ni], 0, 0, 0);
            accu[mi][ni] = __builtin_amdgcn_mfma_f32_16x16x32_bf16(af[mi], bu[ni], accu[mi][ni], 0, 0, 0);
          }
      }
      __syncthreads();
    }
#pragma unroll
    for (int mi = 0; mi < 4; mi++) {
#pragma unroll
      for (int r = 0; r < 4; r++) {
        int lr = wm * 64 + mi * 16 + (l >> 4) * 4 + r;
        int pr = m0 + lr;
        if (pr < ne) {
          float c = (e < 8) ? cwp[e * NTOK + pr] : 1.0f;
#pragma unroll
          for (int ni = 0; ni < 4; ni++) {
            float gv = accg[mi][ni][r];
            float uv = accu[mi][ni][r];
            float val = c * (gv / (1.f + __expf(-gv))) * uv;
            int col = n0 + wn * 64 + ni * 16 + (l & 15);
            Tc[(size_t)(off_e + pr) * I_ + col] = (bf16)val;
          }
        }
      }
    }
  }
}

// ---------------- GEMM2 (grouped, XCD-affine): Yp[off_e+p] = Tc @ WdT_e^T ----------------
__global__ __launch_bounds__(256, 4) void gemm2_kernel(
    const bf16* __restrict__ Tc, const bf16* __restrict__ WdT,
    const int* __restrict__ cnt, bf16* __restrict__ Yp) {
  __shared__ bf16 As[128 * 64], Bs[128 * 64];
  int t = threadIdx.x;
  int l = t & 63, w = t >> 6;
  int wm = w >> 1, wn = w & 1;
  int srow = t >> 3;
  int scol = (((t & 7) ^ ((t >> 3) & 7)) * 8);
  bf16* la = As + w * 512;
  bf16* lb = Bs + w * 512;
  int g = blockIdx.x & 7;
  int S = gridDim.x >> 3;

  for (int j = blockIdx.x >> 3; ; j += S) {
    int e, m0, ne, off_e, n0;
    if (!xcd_decode(cnt, g, j, 8, e, m0, ne, off_e, n0)) break;

    f32x4 acc[4][4];
#pragma unroll
    for (int mi = 0; mi < 4; mi++)
#pragma unroll
      for (int ni = 0; ni < 4; ni++) acc[mi][ni] = (f32x4){0.f, 0.f, 0.f, 0.f};

    const bf16* ga = Tc + (size_t)(off_e + m0 + srow) * I_ + scol;
    const bf16* gb = WdT + (size_t)e * H_ * I_ + (size_t)(n0 + srow) * I_ + scol;

    for (int k0 = 0; k0 < I_; k0 += 64) {
#pragma unroll
      for (int i = 0; i < 4; i++) {
        gload16(ga + (size_t)i * 32 * I_ + k0, la + i * 2048);
        gload16(gb + (size_t)i * 32 * I_ + k0, lb + i * 2048);
      }
      __syncthreads();
#pragma unroll
      for (int ks = 0; ks < 2; ks++) {
        int ko = (((ks * 4 + (l >> 4)) ^ (l & 7)) * 8);
        int ar = wm * 64 + (l & 15);
        int br = wn * 64 + (l & 15);
        bf16x8 af[4], bfv[4];
#pragma unroll
        for (int mi = 0; mi < 4; mi++)
          af[mi] = *(const bf16x8*)(As + (ar + mi * 16) * 64 + ko);
#pragma unroll
        for (int ni = 0; ni < 4; ni++)
          bfv[ni] = *(const bf16x8*)(Bs + (br + ni * 16) * 64 + ko);
#pragma unroll
        for (int mi = 0; mi < 4; mi++)
#pragma unroll
          for (int ni = 0; ni < 4; ni++)
            acc[mi][ni] = __builtin_amdgcn_mfma_f32_16x16x32_bf16(af[mi], bfv[ni], acc[mi][ni], 0, 0, 0);
      }
      __syncthreads();
    }
#pragma unroll
    for (int mi = 0; mi < 4; mi++) {
#pragma unroll
      for (int r = 0; r < 4; r++) {
        int lr = wm * 64 + mi * 16 + (l >> 4) * 4 + r;
        int pr = m0 + lr;
        if (pr < ne) {
#pragma unroll
          for (int ni = 0; ni < 4; ni++) {
            int col = n0 + wn * 64 + ni * 16 + (l & 15);
            Yp[(size_t)(off_e + pr) * H_ + col] = (bf16)acc[mi][ni][r];
          }
        }
      }
    }
  }
}

// ---------------- combine: out[n] = 4 routed partial rows + shared row ----------------
__global__ __launch_bounds__(256) void combine_kernel(
    const int* __restrict__ cnt, const int* __restrict__ tokpos,
    const bf16* __restrict__ Yp, float* __restrict__ out) {
  int t = threadIdx.x;
  int tok = blockIdx.x * 2 + (t >> 7);
  int cb = (t & 127) * 8;
  int off[E_];
  int a = 0;
#pragma unroll
  for (int e = 0; e < E_; e++) { off[e] = a; a += cnt[e]; }
  float sum[8];
  {
    bf16x8 v = *(const bf16x8*)(Yp + (size_t)(32768 + tok) * H_ + cb);
#pragma unroll
    for (int q = 0; q < 8; q++) sum[q] = (float)v[q];
  }
#pragma unroll
  for (int j = 0; j < 4; j++) {
    int tp = tokpos[tok * 4 + j];
    int e = tp >> 13, p = tp & 8191;
    bf16x8 v = *(const bf16x8*)(Yp + (size_t)(off[e] + p) * H_ + cb);
#pragma unroll
    for (int q = 0; q < 8; q++) sum[q] += (float)v[q];
  }
  float* op = out + (size_t)tok * H_ + cb;
  *(f32x4*)(op) = (f32x4){sum[0], sum[1], sum[2], sum[3]};
  *(f32x4*)(op + 4) = (f32x4){sum[4], sum[5], sum[6], sum[7]};
}

extern "C" void kernel_launch(void* const* d_in, const int* in_sizes, int n_in,
                              void* d_out, int out_size, void* d_ws, size_t ws_size,
                              hipStream_t stream) {
  const float* x   = (const float*)d_in[0];
  const float* gw  = (const float*)d_in[1];
  const float* cb  = (const float*)d_in[2];
  const float* Wg  = (const float*)d_in[3];
  const float* Wu  = (const float*)d_in[4];
  const float* Wd  = (const float*)d_in[5];
  const float* Wgs = (const float*)d_in[6];
  const float* Wus = (const float*)d_in[7];
  const float* Wds = (const float*)d_in[8];

  char* ws = (char*)d_ws;
  size_t off = 0;
  int*    cnt    = (int*)(ws + off);    off += 64;
  int*    idx    = (int*)(ws + off);    off += (size_t)E_ * NTOK * 4;
  float*  cwp    = (float*)(ws + off);  off += (size_t)E_ * NTOK * 4;
  int4*   topk_e = (int4*)(ws + off);   off += (size_t)NTOK * 16;
  float4* topk_w = (float4*)(ws + off); off += (size_t)NTOK * 16;
  int*    tokpos = (int*)(ws + off);    off += (size_t)NTOK * 4 * 4;
  bf16* BgT = (bf16*)(ws + off);  off += (size_t)NE * I_ * H_ * 2;
  bf16* BuT = (bf16*)(ws + off);  off += (size_t)NE * I_ * H_ * 2;
  bf16* WdT = (bf16*)(ws + off);  off += (size_t)NE * H_ * I_ * 2;
  bf16* Xb  = (bf16*)(ws + off);  off += (size_t)NTOK * H_ * 2;
  bf16* Tc  = (bf16*)(ws + off);  off += (size_t)NROWS * I_ * 2;
  bf16* Yp  = (bf16*)(ws + off);  off += (size_t)NROWS * H_ * 2;

  hipMemsetAsync(cnt, 0, 64, stream);
  hipLaunchKernelGGL(prep_kernel, dim3(PREP_CONV + PREP_TRANS + NTOK / 4), dim3(256), 0, stream,
                     x, gw, cb, Wg, Wu, Wd, Wgs, Wus, Wds,
                     Xb, BgT, BuT, WdT, topk_e, topk_w);
  hipLaunchKernelGGL(compact_kernel, dim3(NTOK / 256), dim3(256), 0, stream,
                     topk_e, topk_w, cnt, idx, cwp, tokpos);
  hipLaunchKernelGGL(gemm1_kernel, dim3(8 * 160), dim3(256), 0, stream,
                     Xb, BgT, BuT, idx, cwp, cnt, Tc);
  hipLaunchKernelGGL(gemm2_kernel, dim3(8 * 320), dim3(256), 0, stream,
                     Tc, WdT, cnt, Yp);
  hipLaunchKernelGGL(combine_kernel, dim3(NTOK / 2), dim3(256), 0, stream,
                     cnt, tokpos, Yp, (float*)d_out);
}

// Round 9
// 377.615 us; speedup vs baseline: 1.4209x; 1.4209x over previous
//
#include <hip/hip_runtime.h>

#define E_ 8
#define H_ 1024
#define I_ 512
#define NE 9            // 8 routed + 1 shared
#define NTOK 8192
#define NROWS 40960     // 4*NTOK routed + NTOK shared compacted rows

typedef __bf16 bf16;
typedef __bf16 bf16x8 __attribute__((ext_vector_type(8)));
typedef __bf16 bf16x4 __attribute__((ext_vector_type(4)));
typedef float f32x4 __attribute__((ext_vector_type(4)));

__device__ __forceinline__ void gload16(const bf16* g, bf16* l) {
  __builtin_amdgcn_global_load_lds(
      (const __attribute__((address_space(1))) void*)g,
      (__attribute__((address_space(3))) void*)l,
      16, 0, 0);
}

// ---------------- prep: convert (x->bf16) + weight transpose + router ----------------
#define PREP_CONV 2048
#define PREP_TRANS 3456
__global__ __launch_bounds__(256) void prep_kernel(
    const float* __restrict__ x, const float* __restrict__ gw,
    const float* __restrict__ bias,
    const float* __restrict__ Wg, const float* __restrict__ Wu,
    const float* __restrict__ Wd, const float* __restrict__ Wgs,
    const float* __restrict__ Wus, const float* __restrict__ Wds,
    bf16* __restrict__ xb, bf16* __restrict__ BgT, bf16* __restrict__ BuT,
    bf16* __restrict__ WdT, int4* __restrict__ topk_e, float4* __restrict__ topk_w) {
  __shared__ bf16 tile[64][66];
  int bid = blockIdx.x;
  int t = threadIdx.x;

  if (bid < PREP_CONV) {
    size_t base = (size_t)bid * 1024 + t;
#pragma unroll
    for (int j = 0; j < 4; j++) {
      f32x4 v = ((const f32x4*)x)[base + 256 * j];
      bf16x4 o = {(bf16)v.x, (bf16)v.y, (bf16)v.z, (bf16)v.w};
      ((bf16x4*)xb)[base + 256 * j] = o;
    }
    return;
  }
  if (bid < PREP_CONV + PREP_TRANS) {
    int b = bid - PREP_CONV;
    int job = b >> 7;
    int tl = b & 127;
    const float* src;
    bf16* dst;
    int C, dst_ld, tr, tc;
    if (job < 18) {
      int e = job % 9;
      if (job < 9) src = (e < 8) ? Wg + (size_t)e * H_ * I_ : Wgs;
      else         src = (e < 8) ? Wu + (size_t)e * H_ * I_ : Wus;
      dst = ((job < 9) ? BgT : BuT) + (size_t)e * I_ * H_;
      C = I_; dst_ld = H_;
      tr = tl >> 3; tc = tl & 7;
    } else {
      int e = job - 18;
      src = (e < 8) ? Wd + (size_t)e * I_ * H_ : Wds;
      dst = WdT + (size_t)e * H_ * I_;
      C = H_; dst_ld = I_;
      tr = tl >> 4; tc = tl & 15;
    }
    int lx = t & 63, ly = t >> 6;
#pragma unroll
    for (int j = 0; j < 16; j++) {
      int rl = j * 4 + ly;
      tile[lx][rl] = (bf16)src[(size_t)(tr * 64 + rl) * C + tc * 64 + lx];
    }
    __syncthreads();
#pragma unroll
    for (int j = 0; j < 16; j++) {
      int cl = j * 4 + ly;
      dst[(size_t)(tc * 64 + cl) * dst_ld + tr * 64 + lx] = tile[cl][lx];
    }
    return;
  }
  int rb = bid - PREP_CONV - PREP_TRANS;
  int l = t & 63, w = t >> 6;
  int n = rb * 4 + w;
  const f32x4* xr = (const f32x4*)(x + (size_t)n * H_ + l * 16);
  float xv[16];
#pragma unroll
  for (int q = 0; q < 4; q++) {
    f32x4 v = xr[q];
    xv[q * 4 + 0] = v.x; xv[q * 4 + 1] = v.y; xv[q * 4 + 2] = v.z; xv[q * 4 + 3] = v.w;
  }
  float acc[E_];
#pragma unroll
  for (int e = 0; e < E_; e++) {
    const f32x4* gr = (const f32x4*)(gw + e * H_ + l * 16);
    float a = 0.f;
#pragma unroll
    for (int q = 0; q < 4; q++) {
      f32x4 g = gr[q];
      a += xv[q * 4 + 0] * g.x + xv[q * 4 + 1] * g.y + xv[q * 4 + 2] * g.z + xv[q * 4 + 3] * g.w;
    }
    acc[e] = a;
  }
#pragma unroll
  for (int off = 32; off > 0; off >>= 1) {
    float tmp[E_];
#pragma unroll
    for (int e = 0; e < E_; e++) tmp[e] = __shfl_xor(acc[e], off, 64);
#pragma unroll
    for (int e = 0; e < E_; e++) acc[e] += tmp[e];
  }
  if (l == 0) {
    float s[E_], sc[E_];
#pragma unroll
    for (int e = 0; e < E_; e++) {
      s[e] = 1.f / (1.f + __expf(-acc[e]));
      sc[e] = s[e] + bias[e];
    }
    float gs[4];
#pragma unroll
    for (int g = 0; g < 4; g++) gs[g] = sc[2 * g] + sc[2 * g + 1];
    int g0 = 0;
    for (int g = 1; g < 4; g++) if (gs[g] > gs[g0]) g0 = g;
    int g1 = -1;
    for (int g = 0; g < 4; g++) {
      if (g == g0) continue;
      if (g1 < 0 || gs[g] > gs[g1]) g1 = g;
    }
    int es[4] = {2 * g0, 2 * g0 + 1, 2 * g1, 2 * g1 + 1};
    float wsum = 1e-20f;
    for (int j = 0; j < 4; j++) wsum += s[es[j]];
    float inv = 2.5f / wsum;
    topk_e[n] = (int4){es[0], es[1], es[2], es[3]};
    topk_w[n] = (float4){s[es[0]] * inv, s[es[1]] * inv, s[es[2]] * inv, s[es[3]] * inv};
  }
}

// ---------------- compaction ----------------
__global__ __launch_bounds__(256) void compact_kernel(
    const int4* __restrict__ topk_e, const float4* __restrict__ topk_w,
    int* __restrict__ cnt, int* __restrict__ idx, float* __restrict__ cwp,
    int* __restrict__ tokpos) {
  __shared__ int hist[E_];
  __shared__ int base[E_];
  int t = threadIdx.x;
  if (t < E_) hist[t] = 0;
  __syncthreads();
  int n = blockIdx.x * 256 + t;
  int4 e4 = topk_e[n];
  float4 w4 = topk_w[n];
  int le[4] = {e4.x, e4.y, e4.z, e4.w};
  float lw[4] = {w4.x, w4.y, w4.z, w4.w};
  int lpos[4];
#pragma unroll
  for (int j = 0; j < 4; j++) lpos[j] = atomicAdd(&hist[le[j]], 1);
  __syncthreads();
  if (t < E_) base[t] = atomicAdd(&cnt[t], hist[t]);
  __syncthreads();
#pragma unroll
  for (int j = 0; j < 4; j++) {
    int p = base[le[j]] + lpos[j];
    idx[le[j] * NTOK + p] = n;
    cwp[le[j] * NTOK + p] = lw[j];
    tokpos[n * 4 + j] = (le[j] << 13) | p;
  }
}

// slot -> (expert, m0, off_e): scan cnt (gemm2 path, R7-proven).
__device__ __forceinline__ bool slot_decode(const int* cnt, int slot,
                                            int& e, int& m0, int& ne, int& off_e) {
  int off = 0, s = slot;
  for (int ee = 0; ee < NE; ee++) {
    int c = (ee < E_) ? cnt[ee] : NTOK;
    int tl = (c + 127) >> 7;
    if (s < tl) { e = ee; m0 = s * 128; ne = c; off_e = off; return true; }
    s -= tl;
    off += c;
  }
  return false;
}

// XCD-affine decode (gemm1): blocks with blockIdx%8==g handle expert g's
// tiles, then a g-stripe of the shared expert. j = per-XCD work index.
__device__ __forceinline__ bool xcd_decode(const int* cnt, int g, int j, int ntiles,
                                           int& e, int& m0, int& ne, int& off_e, int& n0) {
  int ne_g = cnt[g];
  int Tg = ((ne_g + 127) >> 7) * ntiles;
  if (j < Tg) {
    e = g; ne = ne_g;
    m0 = (j / ntiles) * 128; n0 = (j % ntiles) * 128;
    int off = 0;
    for (int ee = 0; ee < E_; ee++) off += (ee < g) ? cnt[ee] : 0;
    off_e = off;
    return true;
  }
  int s = (j - Tg) * 8 + g;
  if (s < 64 * ntiles) {
    e = 8; ne = NTOK; off_e = 4 * NTOK;
    m0 = (s / ntiles) * 128; n0 = (s % ntiles) * 128;
    return true;
  }
  return false;
}

// LDS tiles [128][64] bf16, XOR-swizzled in 16B chunks (see R2 notes):
// 2-way bank conflicts only (free).

// ---------------- GEMM1 (grouped, XCD-affine, NO launch-bounds-3 — spill!) ----------------
// (256,2): dual accumulator needs 128 f32 regs; (256,3) in R8 spilled to
// scratch (VGPR 84, WRITE_SIZE 659 MB). Keep 2 blocks/CU.
__global__ __launch_bounds__(256, 2) void gemm1_kernel(
    const bf16* __restrict__ X, const bf16* __restrict__ BgT,
    const bf16* __restrict__ BuT, const int* __restrict__ idx,
    const float* __restrict__ cwp, const int* __restrict__ cnt,
    bf16* __restrict__ Tc) {
  __shared__ bf16 As[128 * 64], Bgs[128 * 64], Bus[128 * 64];
  int t = threadIdx.x;
  int l = t & 63, w = t >> 6;
  int wm = w >> 1, wn = w & 1;
  int srow = t >> 3;
  int scol = (((t & 7) ^ ((t >> 3) & 7)) * 8);
  bf16* la = As + w * 512;
  bf16* lg = Bgs + w * 512;
  bf16* lu = Bus + w * 512;
  int g = blockIdx.x & 7;
  int S = gridDim.x >> 3;

  for (int j = blockIdx.x >> 3; ; j += S) {
    int e, m0, ne, off_e, n0;
    if (!xcd_decode(cnt, g, j, 4, e, m0, ne, off_e, n0)) break;

    f32x4 accg[4][4], accu[4][4];
#pragma unroll
    for (int mi = 0; mi < 4; mi++)
#pragma unroll
      for (int ni = 0; ni < 4; ni++) {
        accg[mi][ni] = (f32x4){0.f, 0.f, 0.f, 0.f};
        accu[mi][ni] = (f32x4){0.f, 0.f, 0.f, 0.f};
      }

    int rid[4];
#pragma unroll
    for (int i = 0; i < 4; i++) {
      int r = m0 + srow + 32 * i;
      rid[i] = (e < 8) ? ((r < ne) ? idx[e * NTOK + r] : 0) : r;
    }
    const bf16* gg = BgT + (size_t)e * I_ * H_ + (size_t)(n0 + srow) * H_ + scol;
    const bf16* gu = BuT + (size_t)e * I_ * H_ + (size_t)(n0 + srow) * H_ + scol;

    for (int k0 = 0; k0 < H_; k0 += 64) {
#pragma unroll
      for (int i = 0; i < 4; i++) {
        gload16(X + (size_t)rid[i] * H_ + scol + k0, la + i * 2048);
        gload16(gg + (size_t)i * 32 * H_ + k0, lg + i * 2048);
        gload16(gu + (size_t)i * 32 * H_ + k0, lu + i * 2048);
      }
      __syncthreads();
#pragma unroll
      for (int ks = 0; ks < 2; ks++) {
        int ko = (((ks * 4 + (l >> 4)) ^ (l & 7)) * 8);
        int ar = wm * 64 + (l & 15);
        int br = wn * 64 + (l & 15);
        bf16x8 af[4], bg[4], bu[4];
#pragma unroll
        for (int mi = 0; mi < 4; mi++)
          af[mi] = *(const bf16x8*)(As + (ar + mi * 16) * 64 + ko);
#pragma unroll
        for (int ni = 0; ni < 4; ni++) {
          bg[ni] = *(const bf16x8*)(Bgs + (br + ni * 16) * 64 + ko);
          bu[ni] = *(const bf16x8*)(Bus + (br + ni * 16) * 64 + ko);
        }
#pragma unroll
        for (int mi = 0; mi < 4; mi++)
#pragma unroll
          for (int ni = 0; ni < 4; ni++) {
            accg[mi][ni] = __builtin_amdgcn_mfma_f32_16x16x32_bf16(af[mi], bg[ni], accg[mi][ni], 0, 0, 0);
            accu[mi][ni] = __builtin_amdgcn_mfma_f32_16x16x32_bf16(af[mi], bu[ni], accu[mi][ni], 0, 0, 0);
          }
      }
      __syncthreads();
    }
#pragma unroll
    for (int mi = 0; mi < 4; mi++) {
#pragma unroll
      for (int r = 0; r < 4; r++) {
        int lr = wm * 64 + mi * 16 + (l >> 4) * 4 + r;
        int pr = m0 + lr;
        if (pr < ne) {
          float c = (e < 8) ? cwp[e * NTOK + pr] : 1.0f;
#pragma unroll
          for (int ni = 0; ni < 4; ni++) {
            float gv = accg[mi][ni][r];
            float uv = accu[mi][ni][r];
            float val = c * (gv / (1.f + __expf(-gv))) * uv;
            int col = n0 + wn * 64 + ni * 16 + (l & 15);
            Tc[(size_t)(off_e + pr) * I_ + col] = (bf16)val;
          }
        }
      }
    }
  }
}

// ---------------- GEMM2 (grouped, R7-exact): Yp[off_e+p] = Tc @ WdT_e^T ----------------
__global__ __launch_bounds__(256, 3) void gemm2_kernel(
    const bf16* __restrict__ Tc, const bf16* __restrict__ WdT,
    const int* __restrict__ cnt, bf16* __restrict__ Yp) {
  int e, m0, ne, off_e;
  if (!slot_decode(cnt, blockIdx.y, e, m0, ne, off_e)) return;

  __shared__ bf16 As[128 * 64], Bs[128 * 64];
  int t = threadIdx.x;
  int l = t & 63, w = t >> 6;
  int wm = w >> 1, wn = w & 1;
  int n0 = blockIdx.x * 128;

  f32x4 acc[4][4];
#pragma unroll
  for (int mi = 0; mi < 4; mi++)
#pragma unroll
    for (int ni = 0; ni < 4; ni++) acc[mi][ni] = (f32x4){0.f, 0.f, 0.f, 0.f};

  int srow = t >> 3;
  int scol = (((t & 7) ^ ((t >> 3) & 7)) * 8);
  const bf16* ga = Tc + (size_t)(off_e + m0 + srow) * I_ + scol;
  const bf16* gb = WdT + (size_t)e * H_ * I_ + (size_t)(n0 + srow) * I_ + scol;
  bf16* la = As + w * 512;
  bf16* lb = Bs + w * 512;

  for (int k0 = 0; k0 < I_; k0 += 64) {
#pragma unroll
    for (int i = 0; i < 4; i++) {
      gload16(ga + (size_t)i * 32 * I_ + k0, la + i * 2048);
      gload16(gb + (size_t)i * 32 * I_ + k0, lb + i * 2048);
    }
    __syncthreads();
#pragma unroll
    for (int ks = 0; ks < 2; ks++) {
      int ko = (((ks * 4 + (l >> 4)) ^ (l & 7)) * 8);
      int ar = wm * 64 + (l & 15);
      int br = wn * 64 + (l & 15);
      bf16x8 af[4], bfv[4];
#pragma unroll
      for (int mi = 0; mi < 4; mi++)
        af[mi] = *(const bf16x8*)(As + (ar + mi * 16) * 64 + ko);
#pragma unroll
      for (int ni = 0; ni < 4; ni++)
        bfv[ni] = *(const bf16x8*)(Bs + (br + ni * 16) * 64 + ko);
#pragma unroll
      for (int mi = 0; mi < 4; mi++)
#pragma unroll
        for (int ni = 0; ni < 4; ni++)
          acc[mi][ni] = __builtin_amdgcn_mfma_f32_16x16x32_bf16(af[mi], bfv[ni], acc[mi][ni], 0, 0, 0);
    }
    __syncthreads();
  }
#pragma unroll
  for (int mi = 0; mi < 4; mi++) {
#pragma unroll
    for (int r = 0; r < 4; r++) {
      int lr = wm * 64 + mi * 16 + (l >> 4) * 4 + r;
      int pr = m0 + lr;
      if (pr < ne) {
#pragma unroll
        for (int ni = 0; ni < 4; ni++) {
          int col = n0 + wn * 64 + ni * 16 + (l & 15);
          Yp[(size_t)(off_e + pr) * H_ + col] = (bf16)acc[mi][ni][r];
        }
      }
    }
  }
}

// ---------------- combine: out[n] = 4 routed partial rows + shared row ----------------
__global__ __launch_bounds__(256) void combine_kernel(
    const int* __restrict__ cnt, const int* __restrict__ tokpos,
    const bf16* __restrict__ Yp, float* __restrict__ out) {
  int t = threadIdx.x;
  int tok = blockIdx.x * 2 + (t >> 7);
  int cb = (t & 127) * 8;
  int off[E_];
  int a = 0;
#pragma unroll
  for (int e = 0; e < E_; e++) { off[e] = a; a += cnt[e]; }
  float sum[8];
  {
    bf16x8 v = *(const bf16x8*)(Yp + (size_t)(32768 + tok) * H_ + cb);
#pragma unroll
    for (int q = 0; q < 8; q++) sum[q] = (float)v[q];
  }
#pragma unroll
  for (int j = 0; j < 4; j++) {
    int tp = tokpos[tok * 4 + j];
    int e = tp >> 13, p = tp & 8191;
    bf16x8 v = *(const bf16x8*)(Yp + (size_t)(off[e] + p) * H_ + cb);
#pragma unroll
    for (int q = 0; q < 8; q++) sum[q] += (float)v[q];
  }
  float* op = out + (size_t)tok * H_ + cb;
  *(f32x4*)(op) = (f32x4){sum[0], sum[1], sum[2], sum[3]};
  *(f32x4*)(op + 4) = (f32x4){sum[4], sum[5], sum[6], sum[7]};
}

extern "C" void kernel_launch(void* const* d_in, const int* in_sizes, int n_in,
                              void* d_out, int out_size, void* d_ws, size_t ws_size,
                              hipStream_t stream) {
  const float* x   = (const float*)d_in[0];
  const float* gw  = (const float*)d_in[1];
  const float* cb  = (const float*)d_in[2];
  const float* Wg  = (const float*)d_in[3];
  const float* Wu  = (const float*)d_in[4];
  const float* Wd  = (const float*)d_in[5];
  const float* Wgs = (const float*)d_in[6];
  const float* Wus = (const float*)d_in[7];
  const float* Wds = (const float*)d_in[8];

  char* ws = (char*)d_ws;
  size_t off = 0;
  int*    cnt    = (int*)(ws + off);    off += 64;
  int*    idx    = (int*)(ws + off);    off += (size_t)E_ * NTOK * 4;
  float*  cwp    = (float*)(ws + off);  off += (size_t)E_ * NTOK * 4;
  int4*   topk_e = (int4*)(ws + off);   off += (size_t)NTOK * 16;
  float4* topk_w = (float4*)(ws + off); off += (size_t)NTOK * 16;
  int*    tokpos = (int*)(ws + off);    off += (size_t)NTOK * 4 * 4;
  bf16* BgT = (bf16*)(ws + off);  off += (size_t)NE * I_ * H_ * 2;
  bf16* BuT = (bf16*)(ws + off);  off += (size_t)NE * I_ * H_ * 2;
  bf16* WdT = (bf16*)(ws + off);  off += (size_t)NE * H_ * I_ * 2;
  bf16* Xb  = (bf16*)(ws + off);  off += (size_t)NTOK * H_ * 2;
  bf16* Tc  = (bf16*)(ws + off);  off += (size_t)NROWS * I_ * 2;
  bf16* Yp  = (bf16*)(ws + off);  off += (size_t)NROWS * H_ * 2;

  hipMemsetAsync(cnt, 0, 64, stream);
  hipLaunchKernelGGL(prep_kernel, dim3(PREP_CONV + PREP_TRANS + NTOK / 4), dim3(256), 0, stream,
                     x, gw, cb, Wg, Wu, Wd, Wgs, Wus, Wds,
                     Xb, BgT, BuT, WdT, topk_e, topk_w);
  hipLaunchKernelGGL(compact_kernel, dim3(NTOK / 256), dim3(256), 0, stream,
                     topk_e, topk_w, cnt, idx, cwp, tokpos);
  hipLaunchKernelGGL(gemm1_kernel, dim3(8 * 160), dim3(256), 0, stream,
                     Xb, BgT, BuT, idx, cwp, cnt, Tc);
  hipLaunchKernelGGL(gemm2_kernel, dim3(8, 328), dim3(256), 0, stream,
                     Tc, WdT, cnt, Yp);
  hipLaunchKernelGGL(combine_kernel, dim3(NTOK / 2), dim3(256), 0, stream,
                     cnt, tokpos, Yp, (float*)d_out);
}